// Round 1
// baseline (210.828 us; speedup 1.0000x reference)
//
#include <hip/hip_runtime.h>
#include <hip/hip_bf16.h>

#define TOKENS   16384
#define DMODEL   2048
#define NEXP     64
#define BK       64
#define TB       32      // tokens per block
#define TT       8       // tokens per wave (4 waves)

// out layout (floats): probs[T*2] | indices[T*2] | tokens_per_expert[64] | aux[1]
#define OFF_IDX  (TOKENS * 2)
#define OFF_HIST (TOKENS * 4)
#define OFF_AUX  (TOKENS * 4 + NEXP)

__global__ __launch_bounds__(256) void router_kernel(
    const float* __restrict__ x,      // [T, D]
    const float* __restrict__ gw,     // [E, D]
    float* __restrict__ out,          // full out buffer
    float* __restrict__ probsum_g,    // [64] ws accumulator (zeroed)
    float* __restrict__ hist_g)       // [64] ws accumulator (zeroed)
{
    __shared__ float xs[TB][BK];          // 8 KB
    __shared__ float wt[BK][NEXP + 1];    // 16.25 KB, pad -> 2-way max
    __shared__ float psum_s[4][NEXP];
    __shared__ int   hist_s[NEXP];

    const int tid  = threadIdx.x;
    const int wave = tid >> 6;
    const int lane = tid & 63;
    const int tok0 = blockIdx.x * TB;

    if (tid < NEXP) hist_s[tid] = 0;

    float acc[TT];
#pragma unroll
    for (int t = 0; t < TT; ++t) acc[t] = 0.f;

    for (int k0 = 0; k0 < DMODEL; k0 += BK) {
        __syncthreads();
        // stage X tile: TB x BK = 512 float4, 2 per thread (coalesced rows)
#pragma unroll
        for (int i = 0; i < (TB * BK / 4) / 256; ++i) {
            int idx = tid + i * 256;
            int r = idx >> 4;           // BK/4 = 16 float4 per row
            int c = idx & 15;
            *(float4*)&xs[r][c * 4] =
                *(const float4*)&x[(size_t)(tok0 + r) * DMODEL + k0 + c * 4];
        }
        // stage W tile transposed: E x BK = 1024 float4, 4 per thread
#pragma unroll
        for (int i = 0; i < 4; ++i) {
            int idx = tid + i * 256;
            int e = idx >> 4;
            int c = idx & 15;
            float4 v = *(const float4*)&gw[(size_t)e * DMODEL + k0 + c * 4];
            wt[c * 4 + 0][e] = v.x;
            wt[c * 4 + 1][e] = v.y;
            wt[c * 4 + 2][e] = v.z;
            wt[c * 4 + 3][e] = v.w;
        }
        __syncthreads();

#pragma unroll
        for (int kk4 = 0; kk4 < BK / 4; ++kk4) {
            float w0 = wt[kk4 * 4 + 0][lane];
            float w1 = wt[kk4 * 4 + 1][lane];
            float w2 = wt[kk4 * 4 + 2][lane];
            float w3 = wt[kk4 * 4 + 3][lane];
#pragma unroll
            for (int t = 0; t < TT; ++t) {
                float4 xv = *(const float4*)&xs[wave * TT + t][kk4 * 4];
                acc[t] = fmaf(xv.x, w0, acc[t]);
                acc[t] = fmaf(xv.y, w1, acc[t]);
                acc[t] = fmaf(xv.z, w2, acc[t]);
                acc[t] = fmaf(xv.w, w3, acc[t]);
            }
        }
    }

    // ---- epilogue: per-token softmax + top-2 across the 64 lanes ----
    float local_psum = 0.f;   // per lane == per expert partial sum of probs
    const int tokA = tok0 + wave * TT;

#pragma unroll
    for (int t = 0; t < TT; ++t) {
        float v = acc[t];
        // max over lanes
        float m = v;
#pragma unroll
        for (int off = 32; off; off >>= 1) m = fmaxf(m, __shfl_xor(m, off));
        float ex = __expf(v - m);
        float S = ex;
#pragma unroll
        for (int off = 32; off; off >>= 1) S += __shfl_xor(S, off);
        local_psum += ex / S;

        // top-1 on logits (tie -> lower index, matches lax.top_k)
        float bv = v; int bi = lane;
#pragma unroll
        for (int off = 32; off; off >>= 1) {
            float ov = __shfl_xor(bv, off);
            int   oi = __shfl_xor(bi, off);
            if (ov > bv || (ov == bv && oi < bi)) { bv = ov; bi = oi; }
        }
        float v1 = bv; int i1 = bi;
        // top-2: mask out winner
        float bv2 = (lane == i1) ? -3.4e38f : v; int bi2 = lane;
#pragma unroll
        for (int off = 32; off; off >>= 1) {
            float ov = __shfl_xor(bv2, off);
            int   oi = __shfl_xor(bi2, off);
            if (ov > bv2 || (ov == bv2 && oi < bi2)) { bv2 = ov; bi2 = oi; }
        }
        float v2 = bv2; int i2 = bi2;

        if (lane == 0) {
            float e1 = __expf(v1 - m);
            float e2 = __expf(v2 - m);
            float inv = 1.f / (e1 + e2);
            int tok = tokA + t;
            out[tok * 2 + 0] = e1 * inv;
            out[tok * 2 + 1] = e2 * inv;
            out[OFF_IDX + tok * 2 + 0] = (float)i1;
            out[OFF_IDX + tok * 2 + 1] = (float)i2;
            atomicAdd(&hist_s[i1], 1);
            atomicAdd(&hist_s[i2], 1);
        }
    }

    // block-level reduction of prob sums + histogram, then one atomic each
    psum_s[wave][lane] = local_psum;
    __syncthreads();
    if (wave == 0) {
        float s = psum_s[0][lane] + psum_s[1][lane] + psum_s[2][lane] + psum_s[3][lane];
        atomicAdd(&probsum_g[lane], s);
        atomicAdd(&hist_g[lane], (float)hist_s[lane]);
    }
}

__global__ void finalize_kernel(const float* __restrict__ probsum_g,
                                const float* __restrict__ hist_g,
                                float* __restrict__ out)
{
    int e = threadIdx.x;  // 64 threads
    float tpe = hist_g[e];
    out[OFF_HIST + e] = tpe;
    const float invT = 1.f / (float)TOKENS;
    float term = (tpe * invT) * (probsum_g[e] * invT);
#pragma unroll
    for (int off = 32; off; off >>= 1) term += __shfl_xor(term, off);
    if (e == 0) out[OFF_AUX] = term * (float)NEXP;
}

extern "C" void kernel_launch(void* const* d_in, const int* in_sizes, int n_in,
                              void* d_out, int out_size, void* d_ws, size_t ws_size,
                              hipStream_t stream) {
    const float* x  = (const float*)d_in[0];
    const float* gw = (const float*)d_in[1];
    float* out = (float*)d_out;
    float* ws  = (float*)d_ws;   // probsum[64] | hist[64]

    hipMemsetAsync(d_ws, 0, 128 * sizeof(float), stream);

    dim3 grid(TOKENS / TB);      // 512 blocks
    router_kernel<<<grid, 256, 0, stream>>>(x, gw, out, ws, ws + NEXP);
    finalize_kernel<<<1, 64, 0, stream>>>(ws, ws + NEXP, out);
}